// Round 4
// baseline (36.589 us; speedup 1.0000x reference)
//
#include <hip/hip_runtime.h>

// Problem constants (match the reference file).
#define IN_F   4096
#define OUT_F  4094   // IN_FEATURES - 2
#define BATCH_ 4096
#define WCOLS  3      // min(3, OUT_F)

// clang native vector types — valid for __builtin_nontemporal_{load,store}
typedef float f32x4 __attribute__((ext_vector_type(4)));
typedef float f32x2 __attribute__((ext_vector_type(2)));

// ---------------------------------------------------------------------------
// Single dispatch, role-split blocks, disjoint output addresses (no sync):
//   role<2  (4096 blocks): dot block b -> out[b, 0:3] only
//   role==2 (2048 blocks): fill block  -> zeros cols 3..4093 of 2 rows
// Roles interleaved via blockIdx%3 so read- and write-streams overlap on HBM.
//
// Row byte base = b*4094*4 = b*16376; 16376 % 16 == 8, so:
//   even rows: base%16==0 -> scalar col3, float4 cols 4..4091, float2 col 4092
//   odd  rows: base%16==8 -> scalar col3, float2 cols 4..5, float4 cols 6..4093
// Either parity: 1022 float4 + 1 float2 + 1 scalar covering cols 3..4093.
// ---------------------------------------------------------------------------
__global__ __launch_bounds__(256) void fused_split_kernel(const float* __restrict__ in,
                                                          const float* __restrict__ w,
                                                          const float* __restrict__ bias,
                                                          float* __restrict__ out) {
    const int blk  = blockIdx.x;
    const int tid  = threadIdx.x;
    const int role = blk % 3;

    if (role < 2) {
        // ----------------- dot block: row b -----------------
        const int b = (blk / 3) * 2 + role;   // bijective onto 0..4095

        const f32x4* __restrict__ row = (const f32x4*)(in + (long)b * IN_F);
        const f32x4* __restrict__ w0  = (const f32x4*)(w);
        const f32x4* __restrict__ w1  = (const f32x4*)(w + IN_F);
        const f32x4* __restrict__ w2  = (const f32x4*)(w + 2 * IN_F);

        float s0 = 0.f, s1 = 0.f, s2 = 0.f;

        // IN_F/4 = 1024 float4 per row; 256 threads -> 4 iterations each.
        #pragma unroll 4
        for (int i = tid; i < IN_F / 4; i += 256) {
            f32x4 x = __builtin_nontemporal_load(&row[i]);   // streamed once
            f32x4 a = w0[i];
            f32x4 c = w1[i];
            f32x4 d = w2[i];
            s0 = fmaf(x.x, a.x, fmaf(x.y, a.y, fmaf(x.z, a.z, fmaf(x.w, a.w, s0))));
            s1 = fmaf(x.x, c.x, fmaf(x.y, c.y, fmaf(x.z, c.z, fmaf(x.w, c.w, s1))));
            s2 = fmaf(x.x, d.x, fmaf(x.y, d.y, fmaf(x.z, d.z, fmaf(x.w, d.w, s2))));
        }

        // Wave-level reduction (wave = 64 lanes on gfx950).
        #pragma unroll
        for (int off = 32; off > 0; off >>= 1) {
            s0 += __shfl_down(s0, off);
            s1 += __shfl_down(s1, off);
            s2 += __shfl_down(s2, off);
        }

        __shared__ float red[4][WCOLS];
        const int wave = tid >> 6;
        const int lane = tid & 63;
        if (lane == 0) {
            red[wave][0] = s0;
            red[wave][1] = s1;
            red[wave][2] = s2;
        }
        __syncthreads();

        if (tid < WCOLS) {
            float t = red[0][tid] + red[1][tid] + red[2][tid] + red[3][tid];
            out[(long)b * OUT_F + tid] = t + (float)IN_F * bias[tid];
        }
    } else {
        // ----------------- fill block: rows 2*fb, 2*fb+1, cols 3..4093 -----------------
        const int fb = blk / 3;               // 0..2047
        const f32x4 z4 = {0.f, 0.f, 0.f, 0.f};
        const f32x2 z2 = {0.f, 0.f};

        #pragma unroll
        for (int r = 0; r < 2; ++r) {
            const long rowi = 2L * fb + r;    // parity == r
            float* __restrict__ base = out + rowi * OUT_F;

            if (tid == 0) base[3] = 0.f;                              // scalar edge
            if (tid == 64) *(f32x2*)(base + (r ? 4 : 4092)) = z2;     // float2 edge

            f32x4* __restrict__ p = (f32x4*)(base + (r ? 6 : 4));     // 16B-aligned
            // 1022 float4 = cols {4..4091} (even row) / {6..4093} (odd row)
            for (int i = tid; i < 1022; i += 256) {
                __builtin_nontemporal_store(z4, &p[i]);
            }
        }
    }
}

extern "C" void kernel_launch(void* const* d_in, const int* in_sizes, int n_in,
                              void* d_out, int out_size, void* d_ws, size_t ws_size,
                              hipStream_t stream) {
    const float* in   = (const float*)d_in[0];   // (4096, 4096) fp32
    const float* w    = (const float*)d_in[1];   // (4094, 4096) fp32
    const float* bias = (const float*)d_in[2];   // (4094,) fp32
    float* out = (float*)d_out;                  // (4096, 4094) fp32

    fused_split_kernel<<<6144, 256, 0, stream>>>(in, w, bias, out);
}

// Round 5
// 24.176 us; speedup vs baseline: 1.5134x; 1.5134x over previous
//
#include <hip/hip_runtime.h>

// Problem constants (match the reference file).
#define IN_F   4096
#define OUT_F  4094   // IN_FEATURES - 2
#define BATCH_ 4096
#define WCOLS  3      // min(3, OUT_F)

typedef float f32x4 __attribute__((ext_vector_type(4)));
typedef float f32x2 __attribute__((ext_vector_type(2)));

// ---------------------------------------------------------------------------
// Single dispatch, role-split blocks, disjoint output addresses (no sync):
//   role<2  (4096 blocks): dot block b -> out[b, 0:3] only
//   role==2 (2048 blocks): fill block  -> zeros cols 3..4093 of 2 rows
// All accesses TEMPORAL: input+output (~128 MiB) fit the 256 MiB Infinity
// Cache, so graph-replay steady state runs largely out of L3. (R3/R4's
// nontemporal hints defeated that and regressed 28.5 -> 36 µs.)
//
// Row byte base = b*4094*4 = b*16376; 16376 % 16 == 8, so:
//   even rows: scalar col3, float4 cols 4..4091, float2 cols 4092..4093
//   odd  rows: scalar col3, float2 cols 4..5,    float4 cols 6..4093
// ---------------------------------------------------------------------------
__global__ __launch_bounds__(256) void fused_split_kernel(const float* __restrict__ in,
                                                          const float* __restrict__ w,
                                                          const float* __restrict__ bias,
                                                          float* __restrict__ out) {
    const int blk  = blockIdx.x;
    const int tid  = threadIdx.x;
    const int role = blk % 3;

    if (role < 2) {
        // ----------------- dot block: row b -----------------
        const int b = (blk / 3) * 2 + role;   // bijective onto 0..4095

        const f32x4* __restrict__ row = (const f32x4*)(in + (long)b * IN_F);
        const f32x4* __restrict__ w0  = (const f32x4*)(w);
        const f32x4* __restrict__ w1  = (const f32x4*)(w + IN_F);
        const f32x4* __restrict__ w2  = (const f32x4*)(w + 2 * IN_F);

        float s0 = 0.f, s1 = 0.f, s2 = 0.f;

        // IN_F/4 = 1024 float4 per row; 256 threads -> 4 iterations each.
        #pragma unroll 4
        for (int i = tid; i < IN_F / 4; i += 256) {
            f32x4 x = row[i];
            f32x4 a = w0[i];
            f32x4 c = w1[i];
            f32x4 d = w2[i];
            s0 = fmaf(x.x, a.x, fmaf(x.y, a.y, fmaf(x.z, a.z, fmaf(x.w, a.w, s0))));
            s1 = fmaf(x.x, c.x, fmaf(x.y, c.y, fmaf(x.z, c.z, fmaf(x.w, c.w, s1))));
            s2 = fmaf(x.x, d.x, fmaf(x.y, d.y, fmaf(x.z, d.z, fmaf(x.w, d.w, s2))));
        }

        // Wave-level reduction (wave = 64 lanes on gfx950).
        #pragma unroll
        for (int off = 32; off > 0; off >>= 1) {
            s0 += __shfl_down(s0, off);
            s1 += __shfl_down(s1, off);
            s2 += __shfl_down(s2, off);
        }

        __shared__ float red[4][WCOLS];
        const int wave = tid >> 6;
        const int lane = tid & 63;
        if (lane == 0) {
            red[wave][0] = s0;
            red[wave][1] = s1;
            red[wave][2] = s2;
        }
        __syncthreads();

        if (tid < WCOLS) {
            float t = red[0][tid] + red[1][tid] + red[2][tid] + red[3][tid];
            out[(long)b * OUT_F + tid] = t + (float)IN_F * bias[tid];
        }
    } else {
        // ----------------- fill block: rows 2*fb, 2*fb+1, cols 3..4093 -----------------
        const int fb = blk / 3;               // 0..2047
        const f32x4 z4 = {0.f, 0.f, 0.f, 0.f};
        const f32x2 z2 = {0.f, 0.f};

        #pragma unroll
        for (int r = 0; r < 2; ++r) {
            const long rowi = 2L * fb + r;    // parity == r
            float* __restrict__ base = out + rowi * OUT_F;

            if (tid == 0) base[3] = 0.f;                              // scalar edge
            if (tid == 64) *(f32x2*)(base + (r ? 4 : 4092)) = z2;     // float2 edge

            f32x4* __restrict__ p = (f32x4*)(base + (r ? 6 : 4));     // 16B-aligned
            // 1022 float4 = cols {4..4091} (even row) / {6..4093} (odd row)
            for (int i = tid; i < 1022; i += 256) {
                p[i] = z4;
            }
        }
    }
}

extern "C" void kernel_launch(void* const* d_in, const int* in_sizes, int n_in,
                              void* d_out, int out_size, void* d_ws, size_t ws_size,
                              hipStream_t stream) {
    const float* in   = (const float*)d_in[0];   // (4096, 4096) fp32
    const float* w    = (const float*)d_in[1];   // (4094, 4096) fp32
    const float* bias = (const float*)d_in[2];   // (4094,) fp32
    float* out = (float*)d_out;                  // (4096, 4094) fp32

    fused_split_kernel<<<6144, 256, 0, stream>>>(in, w, bias, out);
}